// Round 3
// baseline (103.773 us; speedup 1.0000x reference)
//
#include <hip/hip_runtime.h>
#include <math.h>

#define IN_C 64
#define OUT_C 128
#define H 56
#define W 56
#define NB 32
#define HW (H*W)
#define KK 576          // IN_C*9
#define EPS 1e-12f
#define PH 58           // padded rows
#define PW 66           // padded cols (56 valid + 8 garbage + 2 halo)

typedef _Float16 half8 __attribute__((ext_vector_type(8)));
typedef float f32x4 __attribute__((ext_vector_type(4)));

// ---------------- kernel 1: per-pixel channel sum of squares ----------------
__global__ __launch_bounds__(256) void k_sumsq(const float* __restrict__ x,
                                               float* __restrict__ s) {
    int P = blockIdx.x * 256 + threadIdx.x;
    if (P >= NB * HW) return;
    int n = P / HW;
    int rem = P - n * HW;
    const float* xp = x + (size_t)n * IN_C * HW + rem;
    float acc = 0.f;
#pragma unroll 8
    for (int c = 0; c < IN_C; ++c) {
        float t = xp[(size_t)c * HW];
        acc += t * t;
    }
    s[P] = acc;
}

// ---------------- kernel 2: 3x3 neighborhood sum -> 1/x_norm ----------------
__global__ __launch_bounds__(256) void k_xnorm(const float* __restrict__ s,
                                               const float* __restrict__ q,
                                               float* __restrict__ inv_xn) {
    int P = blockIdx.x * 256 + threadIdx.x;
    if (P >= NB * HW) return;
    int n = P / HW;
    int rem = P - n * HW;
    int h = rem / W, w = rem - h * W;
    float q2 = q[0] * 0.01f;
    q2 = q2 * q2;
    const float* sp = s + n * HW;
    float acc = 0.f;
#pragma unroll
    for (int di = -1; di <= 1; ++di) {
        int y = h + di;
        if ((unsigned)y >= H) continue;
#pragma unroll
        for (int dj = -1; dj <= 1; ++dj) {
            int xx = w + dj;
            if ((unsigned)xx >= W) continue;
            acc += sp[y * W + xx];
        }
    }
    inv_xn[P] = 1.f / (sqrtf(acc + EPS) + q2);
}

// ---------------- kernel 3: weight prep -------------------------------------
// wt[l][v][c] (fp16) = w[v][c][l] / w_norm[v];  e[v] = (p[v]/10)^2
__global__ __launch_bounds__(64) void k_wprep(const float* __restrict__ w,
                                              const float* __restrict__ p,
                                              const float* __restrict__ q,
                                              _Float16* __restrict__ wt,
                                              float* __restrict__ e) {
    int v = blockIdx.x;
    int lane = threadIdx.x;          // lane = c (64 channels)
    const float* wv = w + v * KK;    // w[v][c*9 + l]
    float acc = 0.f;
#pragma unroll
    for (int j = 0; j < 9; ++j) {
        float t = wv[lane * 9 + j];
        acc += t * t;
    }
#pragma unroll
    for (int off = 32; off > 0; off >>= 1) acc += __shfl_xor(acc, off);
    float q2 = q[0] * 0.01f;
    q2 = q2 * q2;
    float inv = 1.f / (sqrtf(acc + EPS) + q2);
#pragma unroll
    for (int l = 0; l < 9; ++l) {
        wt[((size_t)l * OUT_C + v) * IN_C + lane] = (_Float16)(wv[lane * 9 + l] * inv);
    }
    if (lane == 0) e[v] = p[v] * p[v] * 0.01f;
}

// ---------------- kernel 4: transpose to channels-last padded fp16 ----------
// xcl[n][pr][pc][c], pr in [0,58), pc in [0,66); zero outside valid image.
__global__ __launch_bounds__(256) void k_xpose(const float* __restrict__ x,
                                               _Float16* __restrict__ xcl) {
    __shared__ float lds[64][59];    // stride 59: conflict-free column reads
    int n = blockIdx.y, pr = blockIdx.x;
    int tid = threadIdx.x;
    int h = pr - 1;
    bool rowz = (h < 0 || h >= H);
    {
        int w = tid & 63, c4 = tid >> 6;
        if (!rowz && w < 56) {       // FIX: guard the WRITE (was OOB for w>=59)
#pragma unroll
            for (int cg = 0; cg < 16; ++cg) {
                int c = cg * 4 + c4;
                lds[c][w] = x[((size_t)(n * IN_C + c)) * HW + h * W + w];
            }
        }
    }
    __syncthreads();
    int c = tid & 63, pg = tid >> 6;
    _Float16* dst = xcl + ((size_t)n * PH + pr) * PW * IN_C + c;
#pragma unroll
    for (int pcg = 0; pcg < 17; ++pcg) {
        int pc = pcg * 4 + pg;
        if (pc >= PW) break;
        int w = pc - 1;
        float val = (!rowz && (unsigned)w < W) ? lds[c][w] : 0.f;
        dst[(size_t)pc * IN_C] = (_Float16)val;
    }
}

// ---------------- kernel 5: MFMA layout probe --------------------------------
// P1 = mfma(row-marker, ones)  -> D[m][n] = m  -> m_map[lane][reg]
// P2 = mfma(ones, col-marker)  -> D[m][n] = n  -> n_map[lane][reg]
__global__ __launch_bounds__(64) void k_probe(float* __restrict__ maps) {
    int lane = threadIdx.x;
    half8 mk, ones;
#pragma unroll
    for (int j = 0; j < 8; ++j) {
        mk[j] = (_Float16)(float)(lane & 15);
        ones[j] = (_Float16)(1.0f / 32.0f);
    }
    f32x4 z = (f32x4){0.f, 0.f, 0.f, 0.f};
    f32x4 p1 = __builtin_amdgcn_mfma_f32_16x16x32_f16(mk, ones, z, 0, 0, 0);
    f32x4 p2 = __builtin_amdgcn_mfma_f32_16x16x32_f16(ones, mk, z, 0, 0, 0);
#pragma unroll
    for (int j = 0; j < 4; ++j) {
        maps[lane * 4 + j] = p1[j];          // m of acc slot j
        maps[256 + lane * 4 + j] = p2[j];    // n of acc slot j
    }
}

// ---------------- kernel 6: MFMA conv + epilogue -----------------------------
__global__ __launch_bounds__(256) void k_conv_mfma(
    const _Float16* __restrict__ xcl,   // [NB][PH][PW][64]
    const _Float16* __restrict__ wt,    // [9][128][64]
    const float* __restrict__ inv_xn,   // [NB][HW]
    const float* __restrict__ e,        // [128]
    const float* __restrict__ maps,     // probe maps
    float* __restrict__ out)            // [NB][128][HW]
{
    int tid = threadIdx.x;
    int wv = tid >> 6;
    int lane = tid & 63;
    int n = blockIdx.y;
    int wg = blockIdx.x * 4 + wv;    // 0..111
    int r = wg >> 1;                 // output row 0..55
    int vh = wg & 1;                 // filter half
    int l15 = lane & 15;
    int kg = lane >> 4;              // 0..3

    // probed acc-slot maps (insurance against layout surprises)
    int mm[4], nn[4];
    bool std_layout = true;
#pragma unroll
    for (int j = 0; j < 4; ++j) {
        mm[j] = (int)maps[lane * 4 + j];
        nn[j] = (int)maps[256 + lane * 4 + j];
        std_layout = std_layout && (mm[j] == kg * 4 + j) && (nn[j] == l15);
    }

    f32x4 acc[4][4];
#pragma unroll
    for (int mt = 0; mt < 4; ++mt)
#pragma unroll
        for (int vt = 0; vt < 4; ++vt) acc[mt][vt] = (f32x4){0.f, 0.f, 0.f, 0.f};

#pragma unroll
    for (int l = 0; l < 9; ++l) {
        int di = l / 3, dj = l % 3;
        const _Float16* xrow = xcl
            + (((size_t)n * PH + r + di) * PW + dj + l15) * IN_C + kg * 8;
        const _Float16* wl = wt
            + ((size_t)l * OUT_C + vh * 64 + l15) * IN_C + kg * 8;
#pragma unroll
        for (int k = 0; k < 2; ++k) {        // K-step over c: 2 x 32
            half8 a[4];
#pragma unroll
            for (int mt = 0; mt < 4; ++mt)
                a[mt] = *(const half8*)(xrow + (size_t)mt * 16 * IN_C + k * 32);
#pragma unroll
            for (int vt = 0; vt < 4; ++vt) {
                half8 b = *(const half8*)(wl + (size_t)vt * 16 * IN_C + k * 32);
#pragma unroll
                for (int mt = 0; mt < 4; ++mt)
                    acc[mt][vt] = __builtin_amdgcn_mfma_f32_16x16x32_f16(
                        a[mt], b, acc[mt][vt], 0, 0, 0);
            }
        }
    }

    const float* ixrow = inv_xn + (size_t)n * HW + r * W;
    if (std_layout) {
        // fast path: lane holds cols mt*16+kg*4..+3 for v = vh*64+vt*16+l15
#pragma unroll
        for (int mt = 0; mt < 4; ++mt) {
            int col0 = mt * 16 + kg * 4;
            if (col0 >= W) continue;         // garbage cols 56..63
            float4 ixn = *(const float4*)(ixrow + col0);
            const float* ixp = &ixn.x;
#pragma unroll
            for (int vt = 0; vt < 4; ++vt) {
                int v = vh * 64 + vt * 16 + l15;
                float ev = e[v];
                float4 res;
                float* rp = &res.x;
#pragma unroll
                for (int j = 0; j < 4; ++j) {
                    float z = acc[mt][vt][j] * ixp[j];
                    float mag = fabsf(z) + EPS;
                    float pw = exp2f(ev * log2f(mag));
                    rp[j] = copysignf(pw, z);
                }
                *(float4*)(out + ((size_t)n * OUT_C + v) * HW + r * W + col0) = res;
            }
        }
    } else {
        // layout-agnostic path: probed maps give (pixel, filter) per acc slot
#pragma unroll
        for (int mt = 0; mt < 4; ++mt)
#pragma unroll
            for (int vt = 0; vt < 4; ++vt)
#pragma unroll
                for (int j = 0; j < 4; ++j) {
                    int col = mt * 16 + mm[j];
                    if (col >= W) continue;
                    int v = vh * 64 + vt * 16 + nn[j];
                    float z = acc[mt][vt][j] * ixrow[col];
                    float mag = fabsf(z) + EPS;
                    float pw = exp2f(e[v] * log2f(mag));
                    out[((size_t)n * OUT_C + v) * HW + r * W + col] =
                        copysignf(pw, z);
                }
    }
}

// ---------------- launch ----------------------------------------------------
extern "C" void kernel_launch(void* const* d_in, const int* in_sizes, int n_in,
                              void* d_out, int out_size, void* d_ws, size_t ws_size,
                              hipStream_t stream) {
    const float* x = (const float*)d_in[0];
    const float* w = (const float*)d_in[1];
    const float* p = (const float*)d_in[2];
    const float* q = (const float*)d_in[3];
    float* out = (float*)d_out;

    char* ws = (char*)d_ws;
    float*    s      = (float*)ws;                              // 100352 f
    float*    inv_xn = (float*)(ws + 401408);                   // 100352 f
    float*    e      = (float*)(ws + 802816);                   // 128 f
    float*    maps   = (float*)(ws + 803328);                   // 512 f
    _Float16* wt     = (_Float16*)(ws + 805376);                // 9*128*64 h
    _Float16* xcl    = (_Float16*)(ws + 952832);                // 32*58*66*64 h

    int npix = NB * HW;
    k_sumsq<<<dim3(npix / 256), dim3(256), 0, stream>>>(x, s);
    k_xnorm<<<dim3(npix / 256), dim3(256), 0, stream>>>(s, q, inv_xn);
    k_wprep<<<dim3(OUT_C), dim3(64), 0, stream>>>(w, p, q, wt, e);
    k_xpose<<<dim3(PH, NB), dim3(256), 0, stream>>>(x, xcl);
    k_probe<<<dim3(1), dim3(64), 0, stream>>>(maps);
    k_conv_mfma<<<dim3(28, NB), dim3(256), 0, stream>>>(xcl, wt, inv_xn, e, maps, out);
}

// Round 4
// 55.408 us; speedup vs baseline: 1.8729x; 1.8729x over previous
//
#include <hip/hip_runtime.h>
#include <math.h>
#include <stdint.h>

#define IN_C 64
#define OUT_C 128
#define H 56
#define W 56
#define NB 32
#define HW (H*W)
#define KK 576          // IN_C*9
#define EPS 1e-12f
#define PH 58           // padded rows
#define PW 66           // padded cols (56 valid + halo + garbage margin)

typedef _Float16 half8 __attribute__((ext_vector_type(8)));
typedef float f32x4 __attribute__((ext_vector_type(4)));

// ---------------- kernel 1: transpose to channels-last padded fp16 ----------
// xcl[n][pr][pc][ c ^ ((pc&7)<<3) ]  (pre-swizzled channel index so the conv's
// LDS tile is bank-conflict-free).  Also emits s[n][h][w] = sum_c x^2 (fused).
__global__ __launch_bounds__(256) void k_xpose(const float* __restrict__ x,
                                               _Float16* __restrict__ xcl,
                                               float* __restrict__ s) {
    __shared__ float lds[64][59];    // stride 59: conflict-free column reads
    int n = blockIdx.y, pr = blockIdx.x;
    int tid = threadIdx.x;
    int h = pr - 1;
    bool rowz = (h < 0 || h >= H);
    {
        int w = tid & 63, c4 = tid >> 6;
        if (!rowz && w < 56) {
#pragma unroll
            for (int cg = 0; cg < 16; ++cg) {
                int c = cg * 4 + c4;
                lds[c][w] = x[((size_t)(n * IN_C + c)) * HW + h * W + w];
            }
        }
    }
    __syncthreads();
    int c = tid & 63, pg = tid >> 6;    // wave index == pg; lanes enumerate c
    _Float16* dst = xcl + ((size_t)n * PH + pr) * PW * IN_C;
#pragma unroll
    for (int pcg = 0; pcg < 17; ++pcg) {
        int pc = pcg * 4 + pg;          // uniform within the wave
        if (pc >= PW) break;
        int w = pc - 1;
        bool valid = (!rowz && (unsigned)w < W);
        float val = valid ? lds[c][w] : 0.f;
        dst[(size_t)pc * IN_C + (c ^ ((pc & 7) << 3))] = (_Float16)val;
        // fused sum of squares across the 64 lanes (= all channels)
        float sq = val * val;
#pragma unroll
        for (int off = 32; off > 0; off >>= 1) sq += __shfl_xor(sq, off);
        if (valid && c == 0) s[(size_t)n * HW + h * W + w] = sq;
    }
}

// ---------------- kernel 2: 3x3 neighborhood sum -> 1/x_norm (4 px/thread) --
__global__ __launch_bounds__(256) void k_xnorm(const float* __restrict__ s,
                                               const float* __restrict__ q,
                                               float* __restrict__ inv_xn) {
    int t = blockIdx.x * 256 + threadIdx.x;
    if (t >= NB * HW / 4) return;
    int n = t / (HW / 4);
    int rem = t - n * (HW / 4);
    int p0 = rem * 4;
    int h = p0 / W, w0 = p0 - h * W;     // w0 in {0,4,...,52}
    float q2 = q[0] * 0.01f;
    q2 = q2 * q2;
    const float* sp = s + (size_t)n * HW;
    float a0 = 0.f, a1 = 0.f, a2 = 0.f, a3 = 0.f;
#pragma unroll
    for (int dy = -1; dy <= 1; ++dy) {
        int y = h + dy;
        if ((unsigned)y >= H) continue;
        const float* row = sp + y * W;
        float4 m = *(const float4*)(row + w0);
        float lft = (w0 > 0) ? row[w0 - 1] : 0.f;
        float rgt = (w0 + 4 < W) ? row[w0 + 4] : 0.f;
        a0 += lft + m.x + m.y;
        a1 += m.x + m.y + m.z;
        a2 += m.y + m.z + m.w;
        a3 += m.z + m.w + rgt;
    }
    float4 res;
    res.x = 1.f / (sqrtf(a0 + EPS) + q2);
    res.y = 1.f / (sqrtf(a1 + EPS) + q2);
    res.z = 1.f / (sqrtf(a2 + EPS) + q2);
    res.w = 1.f / (sqrtf(a3 + EPS) + q2);
    *(float4*)(inv_xn + (size_t)n * HW + p0) = res;
}

// ---------------- kernel 3: weight prep -------------------------------------
// wt[l][v][ c ^ ((v&7)<<3) ] (fp16, pre-swizzled) = w[v][c][l] / w_norm[v]
__global__ __launch_bounds__(64) void k_wprep(const float* __restrict__ w,
                                              const float* __restrict__ p,
                                              const float* __restrict__ q,
                                              _Float16* __restrict__ wt,
                                              float* __restrict__ e) {
    int v = blockIdx.x;
    int lane = threadIdx.x;          // lane = c
    const float* wv = w + v * KK;    // w[v][c*9 + l]
    float acc = 0.f;
#pragma unroll
    for (int j = 0; j < 9; ++j) {
        float t = wv[lane * 9 + j];
        acc += t * t;
    }
#pragma unroll
    for (int off = 32; off > 0; off >>= 1) acc += __shfl_xor(acc, off);
    float q2 = q[0] * 0.01f;
    q2 = q2 * q2;
    float inv = 1.f / (sqrtf(acc + EPS) + q2);
    int cs = lane ^ ((v & 7) << 3);
#pragma unroll
    for (int l = 0; l < 9; ++l) {
        wt[((size_t)l * OUT_C + v) * IN_C + cs] = (_Float16)(wv[lane * 9 + l] * inv);
    }
    if (lane == 0) e[v] = p[v] * p[v] * 0.01f;
}

// ---------------- kernel 4: MFMA conv, LDS-staged ----------------------------
// Block: 512 thr (8 waves) = 4 output rows x 64 cols x 128 v.
// Wave (row_rel = wv>>1, vh = wv&1): 4 m-tiles x 4 v-tiles, acc 64 VGPR.
// LDS: x tile 6 rows x 66 x 64c (50.7KB, staged once) + w tap tile 16KB.
// Swizzle: data pre-swizzled in memory; ds_read XORs the k-offset -> no
// bank conflicts. Weight staging is async-split (load l+1 regs during l).
__global__ __launch_bounds__(512, 4) void k_conv_mfma(
    const _Float16* __restrict__ xcl,   // [NB][PH][PW][64] swizzled
    const _Float16* __restrict__ wt,    // [9][128][64] swizzled
    const float* __restrict__ inv_xn,   // [NB][HW]
    const float* __restrict__ e,        // [128]
    float* __restrict__ out)            // [NB][128][HW]
{
    __shared__ __align__(16) _Float16 xls[6 * PW * IN_C];   // 50688 B
    __shared__ __align__(16) _Float16 wls[OUT_C * IN_C];    // 16384 B

    int tid = threadIdx.x;
    int wv = tid >> 6;
    int lane = tid & 63;
    int l15 = lane & 15;
    int kg = lane >> 4;
    int n = blockIdx.y;
    int r0 = blockIdx.x * 4;
    int row_rel = wv >> 1;
    int vh = wv & 1;

    // ---- stage x tile: 3168 16B chunks, reg-staged (coalesced both sides)
    {
        const float4* src = (const float4*)(xcl + ((size_t)n * PH + r0) * PW * IN_C);
        float4* dstv = (float4*)xls;
#pragma unroll
        for (int i = 0; i < 7; ++i) {
            int off = i * 512 + tid;
            if (off < 6 * PW * IN_C / 8) dstv[off] = src[off];
        }
    }

    // ---- preload weights for tap 0 into regs
    float4 wreg0, wreg1;
    {
        const float4* wsrc = (const float4*)wt;
        wreg0 = wsrc[tid];
        wreg1 = wsrc[512 + tid];
    }

    f32x4 acc[4][4];
#pragma unroll
    for (int mt = 0; mt < 4; ++mt)
#pragma unroll
        for (int vt = 0; vt < 4; ++vt) acc[mt][vt] = (f32x4){0.f, 0.f, 0.f, 0.f};

    for (int l = 0; l < 9; ++l) {
        __syncthreads();                 // wls consumers of tap l-1 done
        {                                // commit tap-l weights to LDS
            float4* dstv = (float4*)wls;
            dstv[tid] = wreg0;
            dstv[512 + tid] = wreg1;
        }
        if (l < 8) {                     // async-split: issue tap-l+1 loads now
            const float4* wsrc = (const float4*)(wt + (size_t)(l + 1) * OUT_C * IN_C);
            wreg0 = wsrc[tid];
            wreg1 = wsrc[512 + tid];
        }
        __syncthreads();                 // x (first iter) + w(l) visible

        int di = l / 3, dj = l % 3;
        int pc0 = l15 + dj;
        int xbase = ((row_rel + di) * PW + pc0) * 128;   // byte offset
        int xkey = (pc0 & 7) << 4;
        int wbase = (vh * 64 + l15) * 128;               // byte offset
        int wkey = (l15 & 7) << 4;

#pragma unroll
        for (int k = 0; k < 2; ++k) {
            int koff = k * 64 + kg * 16;
            half8 a[4];
#pragma unroll
            for (int mt = 0; mt < 4; ++mt)
                a[mt] = *(const half8*)((const char*)xls + xbase + mt * 2048 + (koff ^ xkey));
#pragma unroll
            for (int vt = 0; vt < 4; ++vt) {
                half8 b = *(const half8*)((const char*)wls + wbase + vt * 2048 + (koff ^ wkey));
#pragma unroll
                for (int mt = 0; mt < 4; ++mt)
                    acc[mt][vt] = __builtin_amdgcn_mfma_f32_16x16x32_f16(
                        a[mt], b, acc[mt][vt], 0, 0, 0);
            }
        }
    }

    // ---- epilogue: lane holds cols mt*16+kg*4..+3 for v = vh*64+vt*16+l15
    int r = r0 + row_rel;
    const float* ixrow = inv_xn + (size_t)n * HW + r * W;
#pragma unroll
    for (int mt = 0; mt < 4; ++mt) {
        int col0 = mt * 16 + kg * 4;
        if (col0 >= W) continue;         // garbage cols 56..63
        float4 ixn = *(const float4*)(ixrow + col0);
        const float* ixp = &ixn.x;
#pragma unroll
        for (int vt = 0; vt < 4; ++vt) {
            int v = vh * 64 + vt * 16 + l15;
            float ev = e[v];
            float4 res;
            float* rp = &res.x;
#pragma unroll
            for (int j = 0; j < 4; ++j) {
                float z = acc[mt][vt][j] * ixp[j];
                float mag = fabsf(z) + EPS;
                float pw = exp2f(ev * log2f(mag));
                rp[j] = copysignf(pw, z);
            }
            *(float4*)(out + ((size_t)n * OUT_C + v) * HW + r * W + col0) = res;
        }
    }
}

// ---------------- launch ----------------------------------------------------
extern "C" void kernel_launch(void* const* d_in, const int* in_sizes, int n_in,
                              void* d_out, int out_size, void* d_ws, size_t ws_size,
                              hipStream_t stream) {
    const float* x = (const float*)d_in[0];
    const float* w = (const float*)d_in[1];
    const float* p = (const float*)d_in[2];
    const float* q = (const float*)d_in[3];
    float* out = (float*)d_out;

    char* ws = (char*)d_ws;
    float*    s      = (float*)ws;                              // 100352 f
    float*    inv_xn = (float*)(ws + 401408);                   // 100352 f
    float*    e      = (float*)(ws + 802816);                   // 128 f
    _Float16* wt     = (_Float16*)(ws + 803328);                // 9*128*64 h
    _Float16* xcl    = (_Float16*)(ws + 950784);                // 32*58*66*64 h

    k_xpose<<<dim3(PH, NB), dim3(256), 0, stream>>>(x, xcl, s);
    k_xnorm<<<dim3(NB * HW / 4 / 256), dim3(256), 0, stream>>>(s, q, inv_xn);
    k_wprep<<<dim3(OUT_C), dim3(64), 0, stream>>>(w, p, q, wt, e);
    k_conv_mfma<<<dim3(14, NB), dim3(512), 0, stream>>>(xcl, wt, inv_xn, e, out);
}